// Round 1
// baseline (2498.350 us; speedup 1.0000x reference)
//
#include <hip/hip_runtime.h>

#define H_DIM 128
#define IN_DIM 512

static inline size_t align256(size_t x) { return (x + 255) & ~(size_t)255; }

// ---------------- degree / CSR construction ----------------

__global__ void count_deg_kernel(const int* __restrict__ dst, int* __restrict__ cnt, int e) {
    int i = blockIdx.x * blockDim.x + threadIdx.x;
    if (i < e) atomicAdd(&cnt[dst[i]], 1);
}

__global__ void deg_fin_kernel(const int* __restrict__ cnt, float* __restrict__ deg,
                               float* __restrict__ inv_deg, int n) {
    int i = blockIdx.x * blockDim.x + threadIdx.x;
    if (i < n) {
        float d = (float)cnt[i] + 1.0f;
        deg[i] = d;
        inv_deg[i] = 1.0f / d;
    }
}

// 3-kernel exclusive scan over per-node counts -> row_start
__global__ void scan_a_kernel(const int* __restrict__ cnt, int* __restrict__ partial, int n) {
    __shared__ int sm[256];
    int i = blockIdx.x * 256 + threadIdx.x;
    sm[threadIdx.x] = (i < n) ? cnt[i] : 0;
    __syncthreads();
    for (int off = 128; off > 0; off >>= 1) {
        if (threadIdx.x < off) sm[threadIdx.x] += sm[threadIdx.x + off];
        __syncthreads();
    }
    if (threadIdx.x == 0) partial[blockIdx.x] = sm[0];
}

__global__ void scan_b_kernel(int* __restrict__ partial, int nb) {
    __shared__ int sm[512];
    int t = threadIdx.x;
    int v = (t < nb) ? partial[t] : 0;
    sm[t] = v;
    __syncthreads();
    for (int off = 1; off < 512; off <<= 1) {
        int u = (t >= off) ? sm[t - off] : 0;
        __syncthreads();
        sm[t] += u;
        __syncthreads();
    }
    if (t < nb) partial[t] = sm[t] - v;  // exclusive
}

__global__ void scan_c_kernel(const int* __restrict__ cnt, const int* __restrict__ partial,
                              int* __restrict__ row_start, int n) {
    __shared__ int sm[256];
    int i = blockIdx.x * 256 + threadIdx.x;
    int v = (i < n) ? cnt[i] : 0;
    sm[threadIdx.x] = v;
    __syncthreads();
    for (int off = 1; off < 256; off <<= 1) {
        int u = (threadIdx.x >= off) ? sm[threadIdx.x - off] : 0;
        __syncthreads();
        sm[threadIdx.x] += u;
        __syncthreads();
    }
    if (i < n) row_start[i + 1] = partial[blockIdx.x] + sm[threadIdx.x];
    if (i == 0) row_start[0] = 0;
}

__global__ void fill_csr_kernel(const int* __restrict__ src, const int* __restrict__ dst,
                                const float* __restrict__ deg, const int* __restrict__ row_start,
                                int* __restrict__ fill, int* __restrict__ csr_src,
                                float* __restrict__ csr_w, int e) {
    int i = blockIdx.x * blockDim.x + threadIdx.x;
    if (i < e) {
        int s = src[i], d = dst[i];
        int pos = row_start[d] + atomicAdd(&fill[d], 1);
        csr_src[pos] = s;
        csr_w[pos] = 1.0f / sqrtf(deg[s] * deg[d]);
    }
}

// ---------------- encoder GEMM: h = x @ W_enc^T + b; acc = gamma0 * h ----------------
// block 256 threads computes 64 rows x 128 cols; micro-tile 8x4 per thread
__global__ __launch_bounds__(256) void encoder_kernel(
    const float* __restrict__ x, const float* __restrict__ W,
    const float* __restrict__ bias, const float* __restrict__ gammas,
    float* __restrict__ h, float* __restrict__ acc, int n) {
    __shared__ float xs[64][33];
    __shared__ float ws[32][132];
    const int tid = threadIdx.x;
    const int tr = tid >> 5, tc = tid & 31;
    const int row0 = blockIdx.x * 64;
    float av[8][4];
#pragma unroll
    for (int i = 0; i < 8; ++i)
#pragma unroll
        for (int j = 0; j < 4; ++j) av[i][j] = 0.f;

    for (int k0 = 0; k0 < IN_DIM; k0 += 32) {
#pragma unroll
        for (int q = 0; q < 2; ++q) {  // x tile: 64x32 = 512 float4
            int slot = tid * 2 + q;
            int r = slot >> 3, kq = (slot & 7) * 4;
            float4 xv = make_float4(0.f, 0.f, 0.f, 0.f);
            if (row0 + r < n) xv = *(const float4*)&x[(size_t)(row0 + r) * IN_DIM + k0 + kq];
            xs[r][kq + 0] = xv.x; xs[r][kq + 1] = xv.y; xs[r][kq + 2] = xv.z; xs[r][kq + 3] = xv.w;
        }
#pragma unroll
        for (int q = 0; q < 4; ++q) {  // W tile: 128x32 = 1024 float4 (transposed into LDS)
            int slot = tid * 4 + q;
            int c = slot >> 3, kq = (slot & 7) * 4;
            float4 wv = *(const float4*)&W[(size_t)c * IN_DIM + k0 + kq];
            ws[kq + 0][c] = wv.x; ws[kq + 1][c] = wv.y; ws[kq + 2][c] = wv.z; ws[kq + 3][c] = wv.w;
        }
        __syncthreads();
#pragma unroll
        for (int kk = 0; kk < 32; ++kk) {
            float xv[8];
#pragma unroll
            for (int i = 0; i < 8; ++i) xv[i] = xs[tr * 8 + i][kk];
            const float4 wv = *(const float4*)&ws[kk][tc * 4];
#pragma unroll
            for (int i = 0; i < 8; ++i) {
                av[i][0] = fmaf(xv[i], wv.x, av[i][0]);
                av[i][1] = fmaf(xv[i], wv.y, av[i][1]);
                av[i][2] = fmaf(xv[i], wv.z, av[i][2]);
                av[i][3] = fmaf(xv[i], wv.w, av[i][3]);
            }
        }
        __syncthreads();
    }
    const float g0 = gammas[0];
#pragma unroll
    for (int i = 0; i < 8; ++i) {
        int r = row0 + tr * 8 + i;
        if (r < n) {
#pragma unroll
            for (int j = 0; j < 4; ++j) {
                int c = tc * 4 + j;
                float v = av[i][j] + bias[c];
                h[(size_t)r * H_DIM + c] = v;
                acc[(size_t)r * H_DIM + c] = g0 * v;
            }
        }
    }
}

// ---------------- propagation: one wave64 per node, float2 per lane ----------------
// hnew = high_pass ? self - (msg + self/deg) : (msg + self/deg);  acc += gamma_k * hnew
__global__ __launch_bounds__(256) void prop_kernel(
    const int* __restrict__ row_start, const int* __restrict__ csr_src,
    const float* __restrict__ csr_w, const float* __restrict__ inv_deg,
    const float* __restrict__ hin, float* __restrict__ hout,
    float* __restrict__ acc, const float* __restrict__ gammas, int k,
    const int* __restrict__ hpp, int n) {
    const int w = threadIdx.x >> 6;          // wave in block (0..3)
    const int l = threadIdx.x & 63;          // lane
    const int i = blockIdx.x * 4 + w;        // node
    if (i >= n) return;
    const int beg = row_start[i], end = row_start[i + 1];
    const float2* __restrict__ hin2 = (const float2*)hin;
    float2 msg = make_float2(0.f, 0.f);
    for (int e = beg; e < end; ++e) {
        const int s = csr_src[e];
        const float wgt = csr_w[e];
        const float2 v = hin2[(size_t)s * 64 + l];
        msg.x = fmaf(wgt, v.x, msg.x);
        msg.y = fmaf(wgt, v.y, msg.y);
    }
    const float2 self = hin2[(size_t)i * 64 + l];
    const float idg = inv_deg[i];
    float2 a = make_float2(fmaf(self.x, idg, msg.x), fmaf(self.y, idg, msg.y));
    const int hp = *hpp;
    float2 hnew = hp ? make_float2(self.x - a.x, self.y - a.y) : a;
    ((float2*)hout)[(size_t)i * 64 + l] = hnew;
    const float g = gammas[k];
    float2* acc2 = (float2*)acc;
    float2 avv = acc2[(size_t)i * 64 + l];
    avv.x = fmaf(g, hnew.x, avv.x);
    avv.y = fmaf(g, hnew.y, avv.y);
    acc2[(size_t)i * 64 + l] = avv;
}

// ---------------- BatchNorm statistics ----------------

__global__ __launch_bounds__(128) void bn_partial_kernel(const float* __restrict__ acc,
                                                         float* __restrict__ sums, int n, int rpb) {
    int f = threadIdx.x;
    int r0 = blockIdx.x * rpb;
    int r1 = min(r0 + rpb, n);
    float s = 0.f, sq = 0.f;
    for (int r = r0; r < r1; ++r) {
        float v = acc[(size_t)r * H_DIM + f];
        s += v;
        sq = fmaf(v, v, sq);
    }
    atomicAdd(&sums[f], s);
    atomicAdd(&sums[H_DIM + f], sq);
}

// fold BN into output GEMM: W2[o,h] = W_up[o,h]*scale[h]; cvec[o] = b_up[o] + sum_h shift[h]*W_up[o,h]
__global__ __launch_bounds__(128) void bn_prep_kernel(
    const float* __restrict__ sums, const float* __restrict__ bn_gamma,
    const float* __restrict__ bn_beta, const float* __restrict__ W_up,
    const float* __restrict__ b_up, float* __restrict__ W2, float* __restrict__ cvec, int n) {
    __shared__ float ss[128], sh[128];
    int t = threadIdx.x;
    float nf = (float)n;
    float mu = sums[t] / nf;
    float var = sums[H_DIM + t] / nf - mu * mu;
    float sc = bn_gamma[t] / sqrtf(var + 1e-5f);
    float shv = bn_beta[t] - mu * sc;
    ss[t] = sc;
    sh[t] = shv;
    __syncthreads();
    float c = b_up[t];
    for (int hh = 0; hh < H_DIM; ++hh) {
        float wv = W_up[(size_t)t * H_DIM + hh];
        W2[(size_t)t * H_DIM + hh] = wv * ss[hh];
        c = fmaf(wv, sh[hh], c);
    }
    cvec[t] = c;
}

// ---------------- output GEMM + PReLU: out = prelu(acc @ W2^T + cvec) ----------------
__global__ __launch_bounds__(256) void final_kernel(
    const float* __restrict__ acc, const float* __restrict__ W2,
    const float* __restrict__ cvec, const float* __restrict__ alpha_p,
    float* __restrict__ out, int n) {
    __shared__ float xs[64][33];
    __shared__ float ws[32][132];
    const int tid = threadIdx.x;
    const int tr = tid >> 5, tc = tid & 31;
    const int row0 = blockIdx.x * 64;
    float av[8][4];
#pragma unroll
    for (int i = 0; i < 8; ++i)
#pragma unroll
        for (int j = 0; j < 4; ++j) av[i][j] = 0.f;

    for (int k0 = 0; k0 < H_DIM; k0 += 32) {
#pragma unroll
        for (int q = 0; q < 2; ++q) {
            int slot = tid * 2 + q;
            int r = slot >> 3, kq = (slot & 7) * 4;
            float4 xv = make_float4(0.f, 0.f, 0.f, 0.f);
            if (row0 + r < n) xv = *(const float4*)&acc[(size_t)(row0 + r) * H_DIM + k0 + kq];
            xs[r][kq + 0] = xv.x; xs[r][kq + 1] = xv.y; xs[r][kq + 2] = xv.z; xs[r][kq + 3] = xv.w;
        }
#pragma unroll
        for (int q = 0; q < 4; ++q) {
            int slot = tid * 4 + q;
            int c = slot >> 3, kq = (slot & 7) * 4;
            float4 wv = *(const float4*)&W2[(size_t)c * H_DIM + k0 + kq];
            ws[kq + 0][c] = wv.x; ws[kq + 1][c] = wv.y; ws[kq + 2][c] = wv.z; ws[kq + 3][c] = wv.w;
        }
        __syncthreads();
#pragma unroll
        for (int kk = 0; kk < 32; ++kk) {
            float xv[8];
#pragma unroll
            for (int i = 0; i < 8; ++i) xv[i] = xs[tr * 8 + i][kk];
            const float4 wv = *(const float4*)&ws[kk][tc * 4];
#pragma unroll
            for (int i = 0; i < 8; ++i) {
                av[i][0] = fmaf(xv[i], wv.x, av[i][0]);
                av[i][1] = fmaf(xv[i], wv.y, av[i][1]);
                av[i][2] = fmaf(xv[i], wv.z, av[i][2]);
                av[i][3] = fmaf(xv[i], wv.w, av[i][3]);
            }
        }
        __syncthreads();
    }
    const float al = *alpha_p;
#pragma unroll
    for (int i = 0; i < 8; ++i) {
        int r = row0 + tr * 8 + i;
        if (r < n) {
#pragma unroll
            for (int j = 0; j < 4; ++j) {
                int c = tc * 4 + j;
                float v = av[i][j] + cvec[c];
                out[(size_t)r * H_DIM + c] = v > 0.f ? v : al * v;
            }
        }
    }
}

// ---------------- launch ----------------

extern "C" void kernel_launch(void* const* d_in, const int* in_sizes, int n_in,
                              void* d_out, int out_size, void* d_ws, size_t ws_size,
                              hipStream_t stream) {
    const float* x          = (const float*)d_in[0];
    const float* W_enc      = (const float*)d_in[1];
    const float* b_enc      = (const float*)d_in[2];
    const float* gammas     = (const float*)d_in[3];
    const float* bn_gamma   = (const float*)d_in[4];
    const float* bn_beta    = (const float*)d_in[5];
    const float* W_up       = (const float*)d_in[6];
    const float* b_up       = (const float*)d_in[7];
    const float* prelu_al   = (const float*)d_in[8];
    const int*   edge_index = (const int*)d_in[9];
    const int*   high_pass  = (const int*)d_in[10];

    const int H   = in_sizes[2];            // 128
    const int INF = in_sizes[1] / H;        // 512
    const int n   = in_sizes[0] / INF;      // 100000
    const int e   = in_sizes[9] / 2;        // 1600000
    const int K   = in_sizes[3] - 1;        // 10

    const int* src = edge_index;
    const int* dst = edge_index + e;

    char* p = (char*)d_ws;
    auto alloc = [&](size_t bytes) -> char* { char* r = p; p += align256(bytes); return r; };
    int*   cnt       = (int*)alloc((size_t)n * 4);
    int*   fill      = (int*)alloc((size_t)n * 4);
    int*   row_start = (int*)alloc(((size_t)n + 1) * 4);
    int*   partial   = (int*)alloc(4096);
    float* deg       = (float*)alloc((size_t)n * 4);
    float* inv_deg   = (float*)alloc((size_t)n * 4);
    int*   csr_src   = (int*)alloc((size_t)e * 4);
    float* csr_w     = (float*)alloc((size_t)e * 4);
    float* hkA       = (float*)alloc((size_t)n * H * 4);
    float* hkB       = (float*)alloc((size_t)n * H * 4);
    float* acc       = (float*)alloc((size_t)n * H * 4);
    float* sums      = (float*)alloc(256 * 4);
    float* W2        = (float*)alloc((size_t)H * H * 4);
    float* cvec      = (float*)alloc((size_t)H * 4);

    hipMemsetAsync(cnt, 0, (size_t)n * 4, stream);
    hipMemsetAsync(fill, 0, (size_t)n * 4, stream);
    hipMemsetAsync(sums, 0, 256 * 4, stream);

    const int gb_e = (e + 255) / 256;
    const int gb_n = (n + 255) / 256;

    count_deg_kernel<<<gb_e, 256, 0, stream>>>(dst, cnt, e);
    deg_fin_kernel<<<gb_n, 256, 0, stream>>>(cnt, deg, inv_deg, n);
    scan_a_kernel<<<gb_n, 256, 0, stream>>>(cnt, partial, n);
    scan_b_kernel<<<1, 512, 0, stream>>>(partial, gb_n);
    scan_c_kernel<<<gb_n, 256, 0, stream>>>(cnt, partial, row_start, n);
    fill_csr_kernel<<<gb_e, 256, 0, stream>>>(src, dst, deg, row_start, fill, csr_src, csr_w, e);

    const int gb_m = (n + 63) / 64;
    encoder_kernel<<<gb_m, 256, 0, stream>>>(x, W_enc, b_enc, gammas, hkA, acc, n);

    float* cur = hkA;
    float* nxt = hkB;
    for (int k = 1; k <= K; ++k) {
        prop_kernel<<<(n + 3) / 4, 256, 0, stream>>>(row_start, csr_src, csr_w, inv_deg,
                                                     cur, nxt, acc, gammas, k, high_pass, n);
        float* t = cur; cur = nxt; nxt = t;
    }

    const int nb_bn = 512;
    const int rpb = (n + nb_bn - 1) / nb_bn;
    bn_partial_kernel<<<nb_bn, 128, 0, stream>>>(acc, sums, n, rpb);
    bn_prep_kernel<<<1, 128, 0, stream>>>(sums, bn_gamma, bn_beta, W_up, b_up, W2, cvec, n);
    final_kernel<<<gb_m, 256, 0, stream>>>(acc, W2, cvec, prelu_al, (float*)d_out, n);
}

// Round 5
// 1642.103 us; speedup vs baseline: 1.5214x; 1.5214x over previous
//
#include <hip/hip_runtime.h>
#include <hip/hip_fp16.h>

#define H_DIM 128
#define IN_DIM 512

typedef _Float16 half4v __attribute__((ext_vector_type(4)));
typedef _Float16 half8v __attribute__((ext_vector_type(8)));
typedef float f32x4 __attribute__((ext_vector_type(4)));

static inline size_t align256(size_t x) { return (x + 255) & ~(size_t)255; }

// ---------------- degree / CSR construction ----------------

__global__ void count_deg_kernel(const int* __restrict__ dst, int* __restrict__ cnt, int e) {
    int i = blockIdx.x * blockDim.x + threadIdx.x;
    if (i < e) atomicAdd(&cnt[dst[i]], 1);
}

__global__ void deg_fin_kernel(const int* __restrict__ cnt, float* __restrict__ deg,
                               float* __restrict__ inv_deg, int n) {
    int i = blockIdx.x * blockDim.x + threadIdx.x;
    if (i < n) {
        float d = (float)cnt[i] + 1.0f;
        deg[i] = d;
        inv_deg[i] = 1.0f / d;
    }
}

__global__ void scan_a_kernel(const int* __restrict__ cnt, int* __restrict__ partial, int n) {
    __shared__ int sm[256];
    int i = blockIdx.x * 256 + threadIdx.x;
    sm[threadIdx.x] = (i < n) ? cnt[i] : 0;
    __syncthreads();
    for (int off = 128; off > 0; off >>= 1) {
        if (threadIdx.x < off) sm[threadIdx.x] += sm[threadIdx.x + off];
        __syncthreads();
    }
    if (threadIdx.x == 0) partial[blockIdx.x] = sm[0];
}

__global__ void scan_b_kernel(int* __restrict__ partial, int nb) {
    __shared__ int sm[512];
    int t = threadIdx.x;
    int v = (t < nb) ? partial[t] : 0;
    sm[t] = v;
    __syncthreads();
    for (int off = 1; off < 512; off <<= 1) {
        int u = (t >= off) ? sm[t - off] : 0;
        __syncthreads();
        sm[t] += u;
        __syncthreads();
    }
    if (t < nb) partial[t] = sm[t] - v;  // exclusive
}

__global__ void scan_c_kernel(const int* __restrict__ cnt, const int* __restrict__ partial,
                              int* __restrict__ row_start, int n) {
    __shared__ int sm[256];
    int i = blockIdx.x * 256 + threadIdx.x;
    int v = (i < n) ? cnt[i] : 0;
    sm[threadIdx.x] = v;
    __syncthreads();
    for (int off = 1; off < 256; off <<= 1) {
        int u = (threadIdx.x >= off) ? sm[threadIdx.x - off] : 0;
        __syncthreads();
        sm[threadIdx.x] += u;
        __syncthreads();
    }
    if (i < n) row_start[i + 1] = partial[blockIdx.x] + sm[threadIdx.x];
    if (i == 0) row_start[0] = 0;
}

__global__ void fill_csr_kernel(const int* __restrict__ src, const int* __restrict__ dst,
                                const float* __restrict__ deg, const int* __restrict__ row_start,
                                int* __restrict__ fill, int* __restrict__ csr_src,
                                float* __restrict__ csr_w, int e) {
    int i = blockIdx.x * blockDim.x + threadIdx.x;
    if (i < e) {
        int s = src[i], d = dst[i];
        int pos = row_start[d] + atomicAdd(&fill[d], 1);
        csr_src[pos] = s;
        csr_w[pos] = 1.0f / sqrtf(deg[s] * deg[d]);
    }
}

// ---------------- encoder: h = fp16(x @ W^T + b), acc = fp16(g0 * h), MFMA f16 ----------------
// block = 4 waves, tile 64 rows x 128 cols, BK=64, waves in 2x2 (32 rows x 64 cols each)
__global__ __launch_bounds__(256) void encoder_mfma_kernel(
    const float* __restrict__ x, const float* __restrict__ W,
    const float* __restrict__ bias, const float* __restrict__ gammas,
    __half* __restrict__ h, __half* __restrict__ acc, int n) {
    __shared__ _Float16 As[64][64];
    __shared__ _Float16 Bs[128][64];
    const int tid = threadIdx.x;
    const int lane = tid & 63;
    const int wid = tid >> 6;
    const int wm = wid >> 1, wn = wid & 1;
    const int row0 = blockIdx.x * 64;
    const int lr = lane & 15;         // fragment row/col index
    const int lk = (lane >> 4) * 8;   // fragment k base
    f32x4 cacc[2][4];
#pragma unroll
    for (int a = 0; a < 2; ++a)
#pragma unroll
        for (int b = 0; b < 4; ++b) cacc[a][b] = (f32x4){0.f, 0.f, 0.f, 0.f};

    for (int k0 = 0; k0 < IN_DIM; k0 += 64) {
#pragma unroll
        for (int q = 0; q < 4; ++q) {       // A tile: 64x64 floats = 1024 float4
            int slot = tid * 4 + q;
            int r = slot >> 4;
            int kq = (slot & 15) * 4;
            float4 xv = make_float4(0.f, 0.f, 0.f, 0.f);
            if (row0 + r < n) xv = *(const float4*)&x[(size_t)(row0 + r) * IN_DIM + k0 + kq];
            int idx = kq ^ ((r & 7) << 3);  // XOR swizzle (element k <-> pos k^sw, sw mult of 8)
            half4v hv = {(_Float16)xv.x, (_Float16)xv.y, (_Float16)xv.z, (_Float16)xv.w};
            *(half4v*)&As[r][idx] = hv;
        }
#pragma unroll
        for (int q = 0; q < 8; ++q) {       // B tile: 128x64 floats = 2048 float4
            int slot = tid * 8 + q;
            int c = slot >> 4;
            int kq = (slot & 15) * 4;
            float4 wv = *(const float4*)&W[(size_t)c * IN_DIM + k0 + kq];
            int idx = kq ^ ((c & 7) << 3);
            half4v hv = {(_Float16)wv.x, (_Float16)wv.y, (_Float16)wv.z, (_Float16)wv.w};
            *(half4v*)&Bs[c][idx] = hv;
        }
        __syncthreads();
#pragma unroll
        for (int kk = 0; kk < 64; kk += 32) {
            half8v af[2], bf[4];
#pragma unroll
            for (int fm = 0; fm < 2; ++fm) {
                int r = wm * 32 + fm * 16 + lr;
                int kx = (kk + lk) ^ ((r & 7) << 3);
                af[fm] = *(const half8v*)&As[r][kx];
            }
#pragma unroll
            for (int fn = 0; fn < 4; ++fn) {
                int c = wn * 64 + fn * 16 + lr;
                int kx = (kk + lk) ^ ((c & 7) << 3);
                bf[fn] = *(const half8v*)&Bs[c][kx];
            }
#pragma unroll
            for (int fm = 0; fm < 2; ++fm)
#pragma unroll
                for (int fn = 0; fn < 4; ++fn)
                    cacc[fm][fn] = __builtin_amdgcn_mfma_f32_16x16x32_f16(
                        af[fm], bf[fn], cacc[fm][fn], 0, 0, 0);
        }
        __syncthreads();
    }
    const float g0 = gammas[0];
    const int orow = (lane >> 4) * 4;   // C/D: col=lane&15, row=(lane>>4)*4+reg (m89)
#pragma unroll
    for (int fm = 0; fm < 2; ++fm) {
#pragma unroll
        for (int r = 0; r < 4; ++r) {
            int row = row0 + wm * 32 + fm * 16 + orow + r;
            if (row < n) {
#pragma unroll
                for (int fn = 0; fn < 4; ++fn) {
                    int col = wn * 64 + fn * 16 + lr;
                    float v = cacc[fm][fn][r] + bias[col];
                    h[(size_t)row * H_DIM + col] = __float2half(v);
                    acc[(size_t)row * H_DIM + col] = __float2half(g0 * v);
                }
            }
        }
    }
}

// ---------------- propagation: wave per node, half2 per lane, fp32 compute ----------------
__global__ __launch_bounds__(256) void prop_kernel(
    const int* __restrict__ row_start, const int* __restrict__ csr_src,
    const float* __restrict__ csr_w, const float* __restrict__ inv_deg,
    const __half2* __restrict__ hin, __half2* __restrict__ hout,
    __half2* __restrict__ acc, const float* __restrict__ gammas, int k,
    const int* __restrict__ hpp, int n) {
    const int w = threadIdx.x >> 6;
    const int l = threadIdx.x & 63;
    const int i = blockIdx.x * 4 + w;
    if (i >= n) return;
    const int beg = row_start[i], end = row_start[i + 1];
    float mx = 0.f, my = 0.f;
    int e = beg;
    for (; e + 2 <= end; e += 2) {          // 2-way unroll: 2 outstanding gathers
        int s0 = csr_src[e], s1 = csr_src[e + 1];
        float w0 = csr_w[e], w1 = csr_w[e + 1];
        float2 f0 = __half22float2(hin[(size_t)s0 * 64 + l]);
        float2 f1 = __half22float2(hin[(size_t)s1 * 64 + l]);
        mx = fmaf(w0, f0.x, mx); my = fmaf(w0, f0.y, my);
        mx = fmaf(w1, f1.x, mx); my = fmaf(w1, f1.y, my);
    }
    if (e < end) {
        int s0 = csr_src[e];
        float w0 = csr_w[e];
        float2 f0 = __half22float2(hin[(size_t)s0 * 64 + l]);
        mx = fmaf(w0, f0.x, mx); my = fmaf(w0, f0.y, my);
    }
    float2 self = __half22float2(hin[(size_t)i * 64 + l]);
    const float idg = inv_deg[i];
    float ax = fmaf(self.x, idg, mx), ay = fmaf(self.y, idg, my);
    if (*hpp) { ax = self.x - ax; ay = self.y - ay; }
    hout[(size_t)i * 64 + l] = __floats2half2_rn(ax, ay);
    const float g = gammas[k];
    float2 av = __half22float2(acc[(size_t)i * 64 + l]);
    acc[(size_t)i * 64 + l] = __floats2half2_rn(fmaf(g, ax, av.x), fmaf(g, ay, av.y));
}

// ---------------- BatchNorm statistics ----------------

__global__ __launch_bounds__(128) void bn_partial_kernel(const __half* __restrict__ acc,
                                                         float* __restrict__ sums, int n, int rpb) {
    int f = threadIdx.x;
    int r0 = blockIdx.x * rpb;
    int r1 = min(r0 + rpb, n);
    float s = 0.f, sq = 0.f;
    for (int r = r0; r < r1; ++r) {
        float v = __half2float(acc[(size_t)r * H_DIM + f]);
        s += v;
        sq = fmaf(v, v, sq);
    }
    atomicAdd(&sums[f], s);
    atomicAdd(&sums[H_DIM + f], sq);
}

// fold BN into output GEMM: W2h[o,h] = fp16(W_up[o,h]*scale[h]); cvec[o] = b_up[o] + sum_h shift[h]*W_up[o,h]
__global__ __launch_bounds__(128) void bn_prep_kernel(
    const float* __restrict__ sums, const float* __restrict__ bn_gamma,
    const float* __restrict__ bn_beta, const float* __restrict__ W_up,
    const float* __restrict__ b_up, __half* __restrict__ W2h, float* __restrict__ cvec, int n) {
    __shared__ float ss[128], sh[128];
    int t = threadIdx.x;
    float nf = (float)n;
    float mu = sums[t] / nf;
    float var = sums[H_DIM + t] / nf - mu * mu;
    float sc = bn_gamma[t] / sqrtf(var + 1e-5f);
    float shv = bn_beta[t] - mu * sc;
    ss[t] = sc;
    sh[t] = shv;
    __syncthreads();
    float c = b_up[t];
    for (int hh = 0; hh < H_DIM; ++hh) {
        float wv = W_up[(size_t)t * H_DIM + hh];
        W2h[(size_t)t * H_DIM + hh] = __float2half(wv * ss[hh]);
        c = fmaf(wv, sh[hh], c);
    }
    cvec[t] = c;
}

// ---------------- final GEMM + PReLU, MFMA f16, K=128 single tile ----------------
__global__ __launch_bounds__(256) void final_mfma_kernel(
    const __half* __restrict__ accp, const __half* __restrict__ W2,
    const float* __restrict__ cvec, const float* __restrict__ alpha_p,
    float* __restrict__ out, int n) {
    __shared__ _Float16 As[64][128];
    __shared__ _Float16 Bs[128][128];
    const int tid = threadIdx.x;
    const int lane = tid & 63;
    const int wid = tid >> 6;
    const int wm = wid >> 1, wn = wid & 1;
    const int row0 = blockIdx.x * 64;
    const int lr = lane & 15;
    const int lk = (lane >> 4) * 8;
    f32x4 cacc[2][4];
#pragma unroll
    for (int a = 0; a < 2; ++a)
#pragma unroll
        for (int b = 0; b < 4; ++b) cacc[a][b] = (f32x4){0.f, 0.f, 0.f, 0.f};

#pragma unroll
    for (int q = 0; q < 4; ++q) {       // A: 64x128 halves = 1024 x half8v
        int slot = tid * 4 + q;
        int r = slot >> 4;
        int kq = (slot & 15) * 8;       // covers k = 0..127
        half8v av = {(_Float16)0, (_Float16)0, (_Float16)0, (_Float16)0,
                     (_Float16)0, (_Float16)0, (_Float16)0, (_Float16)0};
        if (row0 + r < n) av = *(const half8v*)&accp[(size_t)(row0 + r) * H_DIM + kq];
        int idx = kq ^ ((r & 7) << 3);
        *(half8v*)&As[r][idx] = av;
    }
#pragma unroll
    for (int q = 0; q < 8; ++q) {       // B: 128x128 halves = 2048 x half8v
        int slot = tid * 8 + q;
        int c = slot >> 4;
        int kq = (slot & 15) * 8;       // covers k = 0..127
        half8v wv = *(const half8v*)&W2[(size_t)c * H_DIM + kq];
        int idx = kq ^ ((c & 7) << 3);
        *(half8v*)&Bs[c][idx] = wv;
    }
    __syncthreads();
#pragma unroll
    for (int kk = 0; kk < 128; kk += 32) {
        half8v af[2], bf[4];
#pragma unroll
        for (int fm = 0; fm < 2; ++fm) {
            int r = wm * 32 + fm * 16 + lr;
            int kx = (kk + lk) ^ ((r & 7) << 3);
            af[fm] = *(const half8v*)&As[r][kx];
        }
#pragma unroll
        for (int fn = 0; fn < 4; ++fn) {
            int c = wn * 64 + fn * 16 + lr;
            int kx = (kk + lk) ^ ((c & 7) << 3);
            bf[fn] = *(const half8v*)&Bs[c][kx];
        }
#pragma unroll
        for (int fm = 0; fm < 2; ++fm)
#pragma unroll
            for (int fn = 0; fn < 4; ++fn)
                cacc[fm][fn] = __builtin_amdgcn_mfma_f32_16x16x32_f16(
                    af[fm], bf[fn], cacc[fm][fn], 0, 0, 0);
    }
    const float al = *alpha_p;
    const int orow = (lane >> 4) * 4;
#pragma unroll
    for (int fm = 0; fm < 2; ++fm) {
#pragma unroll
        for (int r = 0; r < 4; ++r) {
            int row = row0 + wm * 32 + fm * 16 + orow + r;
            if (row < n) {
#pragma unroll
                for (int fn = 0; fn < 4; ++fn) {
                    int col = wn * 64 + fn * 16 + lr;
                    float v = cacc[fm][fn][r] + cvec[col];
                    out[(size_t)row * H_DIM + col] = v > 0.f ? v : al * v;
                }
            }
        }
    }
}

// ---------------- launch ----------------

extern "C" void kernel_launch(void* const* d_in, const int* in_sizes, int n_in,
                              void* d_out, int out_size, void* d_ws, size_t ws_size,
                              hipStream_t stream) {
    const float* x          = (const float*)d_in[0];
    const float* W_enc      = (const float*)d_in[1];
    const float* b_enc      = (const float*)d_in[2];
    const float* gammas     = (const float*)d_in[3];
    const float* bn_gamma   = (const float*)d_in[4];
    const float* bn_beta    = (const float*)d_in[5];
    const float* W_up       = (const float*)d_in[6];
    const float* b_up       = (const float*)d_in[7];
    const float* prelu_al   = (const float*)d_in[8];
    const int*   edge_index = (const int*)d_in[9];
    const int*   high_pass  = (const int*)d_in[10];

    const int H   = in_sizes[2];            // 128
    const int INF = in_sizes[1] / H;        // 512
    const int n   = in_sizes[0] / INF;      // 100000
    const int e   = in_sizes[9] / 2;        // 1600000
    const int K   = in_sizes[3] - 1;        // 10

    const int* src = edge_index;
    const int* dst = edge_index + e;

    char* p = (char*)d_ws;
    auto alloc = [&](size_t bytes) -> char* { char* r = p; p += align256(bytes); return r; };
    int*    cnt       = (int*)alloc((size_t)n * 4);
    int*    fill      = (int*)alloc((size_t)n * 4);
    int*    row_start = (int*)alloc(((size_t)n + 1) * 4);
    int*    partial   = (int*)alloc(4096);
    float*  deg       = (float*)alloc((size_t)n * 4);
    float*  inv_deg   = (float*)alloc((size_t)n * 4);
    int*    csr_src   = (int*)alloc((size_t)e * 4);
    float*  csr_w     = (float*)alloc((size_t)e * 4);
    __half* hkA       = (__half*)alloc((size_t)n * H * 2);
    __half* hkB       = (__half*)alloc((size_t)n * H * 2);
    __half* acc       = (__half*)alloc((size_t)n * H * 2);
    float*  sums      = (float*)alloc(256 * 4);
    __half* W2h       = (__half*)alloc((size_t)H * H * 2);
    float*  cvec      = (float*)alloc((size_t)H * 4);

    hipMemsetAsync(cnt, 0, (size_t)n * 4, stream);
    hipMemsetAsync(fill, 0, (size_t)n * 4, stream);
    hipMemsetAsync(sums, 0, 256 * 4, stream);

    const int gb_e = (e + 255) / 256;
    const int gb_n = (n + 255) / 256;

    count_deg_kernel<<<gb_e, 256, 0, stream>>>(dst, cnt, e);
    deg_fin_kernel<<<gb_n, 256, 0, stream>>>(cnt, deg, inv_deg, n);
    scan_a_kernel<<<gb_n, 256, 0, stream>>>(cnt, partial, n);
    scan_b_kernel<<<1, 512, 0, stream>>>(partial, gb_n);
    scan_c_kernel<<<gb_n, 256, 0, stream>>>(cnt, partial, row_start, n);
    fill_csr_kernel<<<gb_e, 256, 0, stream>>>(src, dst, deg, row_start, fill, csr_src, csr_w, e);

    const int gb_m = (n + 63) / 64;
    encoder_mfma_kernel<<<gb_m, 256, 0, stream>>>(x, W_enc, b_enc, gammas, hkA, acc, n);

    __half* cur = hkA;
    __half* nxt = hkB;
    for (int k = 1; k <= K; ++k) {
        prop_kernel<<<(n + 3) / 4, 256, 0, stream>>>(row_start, csr_src, csr_w, inv_deg,
                                                     (const __half2*)cur, (__half2*)nxt,
                                                     (__half2*)acc, gammas, k, high_pass, n);
        __half* t = cur; cur = nxt; nxt = t;
    }

    const int nb_bn = 512;
    const int rpb = (n + nb_bn - 1) / nb_bn;
    bn_partial_kernel<<<nb_bn, 128, 0, stream>>>(acc, sums, n, rpb);
    bn_prep_kernel<<<1, 128, 0, stream>>>(sums, bn_gamma, bn_beta, W_up, b_up, W2h, cvec, n);
    final_mfma_kernel<<<gb_m, 256, 0, stream>>>(acc, W2h, cvec, prelu_al, (float*)d_out, n);
}

// Round 6
// 1300.266 us; speedup vs baseline: 1.9214x; 1.2629x over previous
//
#include <hip/hip_runtime.h>
#include <hip/hip_fp16.h>

#define H_DIM 128
#define IN_DIM 512

typedef _Float16 half4v __attribute__((ext_vector_type(4)));
typedef _Float16 half8v __attribute__((ext_vector_type(8)));
typedef float f32x4 __attribute__((ext_vector_type(4)));

static inline size_t align256(size_t x) { return (x + 255) & ~(size_t)255; }

// ---------------- degree / CSR construction ----------------

__global__ void count_deg_kernel(const int* __restrict__ dst, int* __restrict__ cnt, int e) {
    int i = blockIdx.x * blockDim.x + threadIdx.x;
    if (i < e) atomicAdd(&cnt[dst[i]], 1);
}

__global__ void deg_fin_kernel(const int* __restrict__ cnt, float* __restrict__ deg,
                               float* __restrict__ inv_deg, int n) {
    int i = blockIdx.x * blockDim.x + threadIdx.x;
    if (i < n) {
        float d = (float)cnt[i] + 1.0f;
        deg[i] = d;
        inv_deg[i] = 1.0f / d;
    }
}

__global__ void scan_a_kernel(const int* __restrict__ cnt, int* __restrict__ partial, int n) {
    __shared__ int sm[256];
    int i = blockIdx.x * 256 + threadIdx.x;
    sm[threadIdx.x] = (i < n) ? cnt[i] : 0;
    __syncthreads();
    for (int off = 128; off > 0; off >>= 1) {
        if (threadIdx.x < off) sm[threadIdx.x] += sm[threadIdx.x + off];
        __syncthreads();
    }
    if (threadIdx.x == 0) partial[blockIdx.x] = sm[0];
}

__global__ void scan_b_kernel(int* __restrict__ partial, int nb) {
    __shared__ int sm[512];
    int t = threadIdx.x;
    int v = (t < nb) ? partial[t] : 0;
    sm[t] = v;
    __syncthreads();
    for (int off = 1; off < 512; off <<= 1) {
        int u = (t >= off) ? sm[t - off] : 0;
        __syncthreads();
        sm[t] += u;
        __syncthreads();
    }
    if (t < nb) partial[t] = sm[t] - v;  // exclusive
}

__global__ void scan_c_kernel(const int* __restrict__ cnt, const int* __restrict__ partial,
                              int* __restrict__ row_start, int n) {
    __shared__ int sm[256];
    int i = blockIdx.x * 256 + threadIdx.x;
    int v = (i < n) ? cnt[i] : 0;
    sm[threadIdx.x] = v;
    __syncthreads();
    for (int off = 1; off < 256; off <<= 1) {
        int u = (threadIdx.x >= off) ? sm[threadIdx.x - off] : 0;
        __syncthreads();
        sm[threadIdx.x] += u;
        __syncthreads();
    }
    if (i < n) row_start[i + 1] = partial[blockIdx.x] + sm[threadIdx.x];
    if (i == 0) row_start[0] = 0;
}

// int2 CSR entry: .x = src node, .y = float bits of edge weight (ONE 8B scatter/edge)
__global__ void fill_csr_kernel(const int* __restrict__ src, const int* __restrict__ dst,
                                const float* __restrict__ deg, const int* __restrict__ row_start,
                                int* __restrict__ fill, int2* __restrict__ csr2, int e) {
    int i = blockIdx.x * blockDim.x + threadIdx.x;
    if (i < e) {
        int s = src[i], d = dst[i];
        int pos = row_start[d] + atomicAdd(&fill[d], 1);
        float w = 1.0f / sqrtf(deg[s] * deg[d]);
        csr2[pos] = make_int2(s, __float_as_int(w));
    }
}

// ---------------- encoder: h = fp16(x @ W^T + b), acc = fp16(g0 * h), MFMA f16 ----------------
// reg-prefetch pipeline: issue next tile's global loads after barrier, before MFMA
__global__ __launch_bounds__(256) void encoder_mfma_kernel(
    const float* __restrict__ x, const float* __restrict__ W,
    const float* __restrict__ bias, const float* __restrict__ gammas,
    __half* __restrict__ h, __half* __restrict__ acc, int n) {
    __shared__ _Float16 As[64][64];
    __shared__ _Float16 Bs[128][64];
    const int tid = threadIdx.x;
    const int lane = tid & 63;
    const int wid = tid >> 6;
    const int wm = wid >> 1, wn = wid & 1;
    const int row0 = blockIdx.x * 64;
    const int lr = lane & 15;         // fragment row/col index
    const int lk = (lane >> 4) * 8;   // fragment k base
    f32x4 cacc[2][4];
#pragma unroll
    for (int a = 0; a < 2; ++a)
#pragma unroll
        for (int b = 0; b < 4; ++b) cacc[a][b] = (f32x4){0.f, 0.f, 0.f, 0.f};

    float4 xr[4], wr[8];
    // load first tile (k0 = 0) into registers
#pragma unroll
    for (int q = 0; q < 4; ++q) {
        int slot = tid * 4 + q;
        int r = slot >> 4, kq = (slot & 15) * 4;
        xr[q] = make_float4(0.f, 0.f, 0.f, 0.f);
        if (row0 + r < n) xr[q] = *(const float4*)&x[(size_t)(row0 + r) * IN_DIM + kq];
    }
#pragma unroll
    for (int q = 0; q < 8; ++q) {
        int slot = tid * 8 + q;
        int c = slot >> 4, kq = (slot & 15) * 4;
        wr[q] = *(const float4*)&W[(size_t)c * IN_DIM + kq];
    }

    for (int k0 = 0; k0 < IN_DIM; k0 += 64) {
        // stage current regs -> LDS (fp32->fp16 convert)
#pragma unroll
        for (int q = 0; q < 4; ++q) {
            int slot = tid * 4 + q;
            int r = slot >> 4, kq = (slot & 15) * 4;
            int idx = kq ^ ((r & 7) << 3);
            half4v hv = {(_Float16)xr[q].x, (_Float16)xr[q].y, (_Float16)xr[q].z, (_Float16)xr[q].w};
            *(half4v*)&As[r][idx] = hv;
        }
#pragma unroll
        for (int q = 0; q < 8; ++q) {
            int slot = tid * 8 + q;
            int c = slot >> 4, kq = (slot & 15) * 4;
            int idx = kq ^ ((c & 7) << 3);
            half4v hv = {(_Float16)wr[q].x, (_Float16)wr[q].y, (_Float16)wr[q].z, (_Float16)wr[q].w};
            *(half4v*)&Bs[c][idx] = hv;
        }
        __syncthreads();
        // prefetch next tile into regs; latency hides under the MFMA section below
        if (k0 + 64 < IN_DIM) {
            int kn = k0 + 64;
#pragma unroll
            for (int q = 0; q < 4; ++q) {
                int slot = tid * 4 + q;
                int r = slot >> 4, kq = (slot & 15) * 4;
                xr[q] = make_float4(0.f, 0.f, 0.f, 0.f);
                if (row0 + r < n) xr[q] = *(const float4*)&x[(size_t)(row0 + r) * IN_DIM + kn + kq];
            }
#pragma unroll
            for (int q = 0; q < 8; ++q) {
                int slot = tid * 8 + q;
                int c = slot >> 4, kq = (slot & 15) * 4;
                wr[q] = *(const float4*)&W[(size_t)c * IN_DIM + kn + kq];
            }
        }
#pragma unroll
        for (int kk = 0; kk < 64; kk += 32) {
            half8v af[2], bf[4];
#pragma unroll
            for (int fm = 0; fm < 2; ++fm) {
                int r = wm * 32 + fm * 16 + lr;
                int kx = (kk + lk) ^ ((r & 7) << 3);
                af[fm] = *(const half8v*)&As[r][kx];
            }
#pragma unroll
            for (int fn = 0; fn < 4; ++fn) {
                int c = wn * 64 + fn * 16 + lr;
                int kx = (kk + lk) ^ ((c & 7) << 3);
                bf[fn] = *(const half8v*)&Bs[c][kx];
            }
#pragma unroll
            for (int fm = 0; fm < 2; ++fm)
#pragma unroll
                for (int fn = 0; fn < 4; ++fn)
                    cacc[fm][fn] = __builtin_amdgcn_mfma_f32_16x16x32_f16(
                        af[fm], bf[fn], cacc[fm][fn], 0, 0, 0);
        }
        __syncthreads();
    }
    const float g0 = gammas[0];
    const int orow = (lane >> 4) * 4;   // C/D: col=lane&15, row=(lane>>4)*4+reg (m89)
#pragma unroll
    for (int fm = 0; fm < 2; ++fm) {
#pragma unroll
        for (int r = 0; r < 4; ++r) {
            int row = row0 + wm * 32 + fm * 16 + orow + r;
            if (row < n) {
#pragma unroll
                for (int fn = 0; fn < 4; ++fn) {
                    int col = wn * 64 + fn * 16 + lr;
                    float v = cacc[fm][fn][r] + bias[col];
                    h[(size_t)row * H_DIM + col] = __float2half(v);
                    acc[(size_t)row * H_DIM + col] = __float2half(g0 * v);
                }
            }
        }
    }
}

// ---------------- propagation: wave per node; 4 edges per gather instruction ----------------
// 16-lane group g reads edge (e+g)'s row as half8 (16B/lane x 16 lanes = 256B row).
// msg accumulated per-group in fp32, reduced via shfl_xor(16,32).
__global__ __launch_bounds__(256) void prop_kernel(
    const int* __restrict__ row_start, const int2* __restrict__ csr2,
    const float* __restrict__ inv_deg,
    const __half* __restrict__ hin, __half* __restrict__ hout,
    __half* __restrict__ acc, const float* __restrict__ gammas, int k,
    const int* __restrict__ hpp, int n) {
    const int w = threadIdx.x >> 6;
    const int l = threadIdx.x & 63;
    const int g = l >> 4;        // edge slot within batch of 4
    const int sub = l & 15;      // 8-feature chunk index
    const int i = blockIdx.x * 4 + w;
    if (i >= n) return;
    const int beg = row_start[i], end = row_start[i + 1];
    const half8v* __restrict__ hin8 = (const half8v*)hin;
    float msg[8];
#pragma unroll
    for (int j = 0; j < 8; ++j) msg[j] = 0.f;
    int e = beg;
    // main loop: 8 edges per iteration (2 batches of 4), no clamping needed
    for (; e + 8 <= end; e += 8) {
        int2 p0 = csr2[e + g];
        int2 p1 = csr2[e + 4 + g];
        half8v v0 = hin8[(size_t)p0.x * 16 + sub];
        half8v v1 = hin8[(size_t)p1.x * 16 + sub];
        float w0 = __int_as_float(p0.y), w1 = __int_as_float(p1.y);
#pragma unroll
        for (int j = 0; j < 8; ++j) {
            msg[j] = fmaf(w0, (float)v0[j], msg[j]);
            msg[j] = fmaf(w1, (float)v1[j], msg[j]);
        }
    }
    // tail: batches of 4 with index clamp + zeroed weight
    for (; e < end; e += 4) {
        int idx = e + g;
        int cidx = idx < end ? idx : end - 1;
        int2 p = csr2[cidx];
        float wgt = idx < end ? __int_as_float(p.y) : 0.f;
        half8v v = hin8[(size_t)p.x * 16 + sub];
#pragma unroll
        for (int j = 0; j < 8; ++j) msg[j] = fmaf(wgt, (float)v[j], msg[j]);
    }
    // reduce the 4 edge-groups: lanes l, l^16, l^32, l^48 hold same feature slots
#pragma unroll
    for (int j = 0; j < 8; ++j) {
        float m = msg[j];
        m += __shfl_xor(m, 16);
        m += __shfl_xor(m, 32);
        msg[j] = m;
    }
    const float idg = inv_deg[i];
    const half8v s8 = hin8[(size_t)i * 16 + sub];
    const int hp = *hpp;
    float hnew[8];
#pragma unroll
    for (int j = 0; j < 8; ++j) {
        float sf = (float)s8[j];
        float a = fmaf(sf, idg, msg[j]);
        hnew[j] = hp ? (sf - a) : a;
    }
    half8v* hout8 = (half8v*)hout;
    half8v* acc8 = (half8v*)acc;
    if (g == 0) {                       // group 0: write hout
        half8v h8;
#pragma unroll
        for (int j = 0; j < 8; ++j) h8[j] = (_Float16)hnew[j];
        hout8[(size_t)i * 16 + sub] = h8;
    } else if (g == 1) {                // group 1: acc RMW in parallel
        const float gm = gammas[k];
        half8v av = acc8[(size_t)i * 16 + sub];
        half8v r;
#pragma unroll
        for (int j = 0; j < 8; ++j) r[j] = (_Float16)fmaf(gm, hnew[j], (float)av[j]);
        acc8[(size_t)i * 16 + sub] = r;
    }
}

// ---------------- BatchNorm statistics ----------------

__global__ __launch_bounds__(128) void bn_partial_kernel(const __half* __restrict__ acc,
                                                         float* __restrict__ sums, int n, int rpb) {
    int f = threadIdx.x;
    int r0 = blockIdx.x * rpb;
    int r1 = min(r0 + rpb, n);
    float s = 0.f, sq = 0.f;
    for (int r = r0; r < r1; ++r) {
        float v = __half2float(acc[(size_t)r * H_DIM + f]);
        s += v;
        sq = fmaf(v, v, sq);
    }
    atomicAdd(&sums[f], s);
    atomicAdd(&sums[H_DIM + f], sq);
}

// fold BN into output GEMM: W2h[o,h] = fp16(W_up[o,h]*scale[h]); cvec[o] = b_up[o] + sum_h shift[h]*W_up[o,h]
__global__ __launch_bounds__(128) void bn_prep_kernel(
    const float* __restrict__ sums, const float* __restrict__ bn_gamma,
    const float* __restrict__ bn_beta, const float* __restrict__ W_up,
    const float* __restrict__ b_up, __half* __restrict__ W2h, float* __restrict__ cvec, int n) {
    __shared__ float ss[128], sh[128];
    int t = threadIdx.x;
    float nf = (float)n;
    float mu = sums[t] / nf;
    float var = sums[H_DIM + t] / nf - mu * mu;
    float sc = bn_gamma[t] / sqrtf(var + 1e-5f);
    float shv = bn_beta[t] - mu * sc;
    ss[t] = sc;
    sh[t] = shv;
    __syncthreads();
    float c = b_up[t];
    for (int hh = 0; hh < H_DIM; ++hh) {
        float wv = W_up[(size_t)t * H_DIM + hh];
        W2h[(size_t)t * H_DIM + hh] = __float2half(wv * ss[hh]);
        c = fmaf(wv, sh[hh], c);
    }
    cvec[t] = c;
}

// ---------------- final GEMM + PReLU, MFMA f16, K=128 single tile ----------------
__global__ __launch_bounds__(256) void final_mfma_kernel(
    const __half* __restrict__ accp, const __half* __restrict__ W2,
    const float* __restrict__ cvec, const float* __restrict__ alpha_p,
    float* __restrict__ out, int n) {
    __shared__ _Float16 As[64][128];
    __shared__ _Float16 Bs[128][128];
    const int tid = threadIdx.x;
    const int lane = tid & 63;
    const int wid = tid >> 6;
    const int wm = wid >> 1, wn = wid & 1;
    const int row0 = blockIdx.x * 64;
    const int lr = lane & 15;
    const int lk = (lane >> 4) * 8;
    f32x4 cacc[2][4];
#pragma unroll
    for (int a = 0; a < 2; ++a)
#pragma unroll
        for (int b = 0; b < 4; ++b) cacc[a][b] = (f32x4){0.f, 0.f, 0.f, 0.f};

#pragma unroll
    for (int q = 0; q < 4; ++q) {       // A: 64x128 halves = 1024 x half8v
        int slot = tid * 4 + q;
        int r = slot >> 4;
        int kq = (slot & 15) * 8;       // covers k = 0..127
        half8v av = {(_Float16)0, (_Float16)0, (_Float16)0, (_Float16)0,
                     (_Float16)0, (_Float16)0, (_Float16)0, (_Float16)0};
        if (row0 + r < n) av = *(const half8v*)&accp[(size_t)(row0 + r) * H_DIM + kq];
        int idx = kq ^ ((r & 7) << 3);
        *(half8v*)&As[r][idx] = av;
    }
#pragma unroll
    for (int q = 0; q < 8; ++q) {       // B: 128x128 halves = 2048 x half8v
        int slot = tid * 8 + q;
        int c = slot >> 4;
        int kq = (slot & 15) * 8;       // covers k = 0..127
        half8v wv = *(const half8v*)&W2[(size_t)c * H_DIM + kq];
        int idx = kq ^ ((c & 7) << 3);
        *(half8v*)&Bs[c][idx] = wv;
    }
    __syncthreads();
#pragma unroll
    for (int kk = 0; kk < 128; kk += 32) {
        half8v af[2], bf[4];
#pragma unroll
        for (int fm = 0; fm < 2; ++fm) {
            int r = wm * 32 + fm * 16 + lr;
            int kx = (kk + lk) ^ ((r & 7) << 3);
            af[fm] = *(const half8v*)&As[r][kx];
        }
#pragma unroll
        for (int fn = 0; fn < 4; ++fn) {
            int c = wn * 64 + fn * 16 + lr;
            int kx = (kk + lk) ^ ((c & 7) << 3);
            bf[fn] = *(const half8v*)&Bs[c][kx];
        }
#pragma unroll
        for (int fm = 0; fm < 2; ++fm)
#pragma unroll
            for (int fn = 0; fn < 4; ++fn)
                cacc[fm][fn] = __builtin_amdgcn_mfma_f32_16x16x32_f16(
                    af[fm], bf[fn], cacc[fm][fn], 0, 0, 0);
    }
    const float al = *alpha_p;
    const int orow = (lane >> 4) * 4;
#pragma unroll
    for (int fm = 0; fm < 2; ++fm) {
#pragma unroll
        for (int r = 0; r < 4; ++r) {
            int row = row0 + wm * 32 + fm * 16 + orow + r;
            if (row < n) {
#pragma unroll
                for (int fn = 0; fn < 4; ++fn) {
                    int col = wn * 64 + fn * 16 + lr;
                    float v = cacc[fm][fn][r] + cvec[col];
                    out[(size_t)row * H_DIM + col] = v > 0.f ? v : al * v;
                }
            }
        }
    }
}

// ---------------- launch ----------------

extern "C" void kernel_launch(void* const* d_in, const int* in_sizes, int n_in,
                              void* d_out, int out_size, void* d_ws, size_t ws_size,
                              hipStream_t stream) {
    const float* x          = (const float*)d_in[0];
    const float* W_enc      = (const float*)d_in[1];
    const float* b_enc      = (const float*)d_in[2];
    const float* gammas     = (const float*)d_in[3];
    const float* bn_gamma   = (const float*)d_in[4];
    const float* bn_beta    = (const float*)d_in[5];
    const float* W_up       = (const float*)d_in[6];
    const float* b_up       = (const float*)d_in[7];
    const float* prelu_al   = (const float*)d_in[8];
    const int*   edge_index = (const int*)d_in[9];
    const int*   high_pass  = (const int*)d_in[10];

    const int H   = in_sizes[2];            // 128
    const int INF = in_sizes[1] / H;        // 512
    const int n   = in_sizes[0] / INF;      // 100000
    const int e   = in_sizes[9] / 2;        // 1600000
    const int K   = in_sizes[3] - 1;        // 10

    const int* src = edge_index;
    const int* dst = edge_index + e;

    char* p = (char*)d_ws;
    auto alloc = [&](size_t bytes) -> char* { char* r = p; p += align256(bytes); return r; };
    int*    cnt       = (int*)alloc((size_t)n * 4);
    int*    fill      = (int*)alloc((size_t)n * 4);
    int*    row_start = (int*)alloc(((size_t)n + 1) * 4);
    int*    partial   = (int*)alloc(4096);
    float*  deg       = (float*)alloc((size_t)n * 4);
    float*  inv_deg   = (float*)alloc((size_t)n * 4);
    int2*   csr2      = (int2*)alloc(((size_t)e + 8) * 8);   // +8 pad for clamped tail reads
    __half* hkA       = (__half*)alloc((size_t)n * H * 2);
    __half* hkB       = (__half*)alloc((size_t)n * H * 2);
    __half* acc       = (__half*)alloc((size_t)n * H * 2);
    float*  sums      = (float*)alloc(256 * 4);
    __half* W2h       = (__half*)alloc((size_t)H * H * 2);
    float*  cvec      = (float*)alloc((size_t)H * 4);

    hipMemsetAsync(cnt, 0, (size_t)n * 4, stream);
    hipMemsetAsync(fill, 0, (size_t)n * 4, stream);
    hipMemsetAsync(sums, 0, 256 * 4, stream);

    const int gb_e = (e + 255) / 256;
    const int gb_n = (n + 255) / 256;

    count_deg_kernel<<<gb_e, 256, 0, stream>>>(dst, cnt, e);
    deg_fin_kernel<<<gb_n, 256, 0, stream>>>(cnt, deg, inv_deg, n);
    scan_a_kernel<<<gb_n, 256, 0, stream>>>(cnt, partial, n);
    scan_b_kernel<<<1, 512, 0, stream>>>(partial, gb_n);
    scan_c_kernel<<<gb_n, 256, 0, stream>>>(cnt, partial, row_start, n);
    fill_csr_kernel<<<gb_e, 256, 0, stream>>>(src, dst, deg, row_start, fill, csr2, e);

    const int gb_m = (n + 63) / 64;
    encoder_mfma_kernel<<<gb_m, 256, 0, stream>>>(x, W_enc, b_enc, gammas, hkA, acc, n);

    __half* cur = hkA;
    __half* nxt = hkB;
    for (int k = 1; k <= K; ++k) {
        prop_kernel<<<(n + 3) / 4, 256, 0, stream>>>(row_start, csr2, inv_deg,
                                                     cur, nxt, acc, gammas, k, high_pass, n);
        __half* t = cur; cur = nxt; nxt = t;
    }

    const int nb_bn = 512;
    const int rpb = (n + nb_bn - 1) / nb_bn;
    bn_partial_kernel<<<nb_bn, 128, 0, stream>>>(acc, sums, n, rpb);
    bn_prep_kernel<<<1, 128, 0, stream>>>(sums, bn_gamma, bn_beta, W_up, b_up, W2h, cvec, n);
    final_mfma_kernel<<<gb_m, 256, 0, stream>>>(acc, W2h, cvec, prelu_al, (float*)d_out, n);
}

// Round 7
// 1265.272 us; speedup vs baseline: 1.9746x; 1.0277x over previous
//
#include <hip/hip_runtime.h>
#include <hip/hip_fp16.h>

#define H_DIM 128
#define IN_DIM 512

typedef _Float16 half4v __attribute__((ext_vector_type(4)));
typedef _Float16 half8v __attribute__((ext_vector_type(8)));
typedef float f32x4 __attribute__((ext_vector_type(4)));

static inline size_t align256(size_t x) { return (x + 255) & ~(size_t)255; }

__device__ inline void gload_lds16(const void* g, void* l) {
    __builtin_amdgcn_global_load_lds(
        (const __attribute__((address_space(1))) unsigned int*)g,
        (__attribute__((address_space(3))) unsigned int*)l, 16, 0, 0);
}

// ---------------- degree / CSR construction ----------------

__global__ void count_deg_kernel(const int* __restrict__ dst, int* __restrict__ cnt, int e) {
    int i = blockIdx.x * blockDim.x + threadIdx.x;
    if (i < e) atomicAdd(&cnt[dst[i]], 1);
}

__global__ void deg_fin_kernel(const int* __restrict__ cnt, float* __restrict__ deg,
                               float* __restrict__ inv_deg, int n) {
    int i = blockIdx.x * blockDim.x + threadIdx.x;
    if (i < n) {
        float d = (float)cnt[i] + 1.0f;
        deg[i] = d;
        inv_deg[i] = 1.0f / d;
    }
}

__global__ void scan_a_kernel(const int* __restrict__ cnt, int* __restrict__ partial, int n) {
    __shared__ int sm[256];
    int i = blockIdx.x * 256 + threadIdx.x;
    sm[threadIdx.x] = (i < n) ? cnt[i] : 0;
    __syncthreads();
    for (int off = 128; off > 0; off >>= 1) {
        if (threadIdx.x < off) sm[threadIdx.x] += sm[threadIdx.x + off];
        __syncthreads();
    }
    if (threadIdx.x == 0) partial[blockIdx.x] = sm[0];
}

__global__ void scan_b_kernel(int* __restrict__ partial, int nb) {
    __shared__ int sm[512];
    int t = threadIdx.x;
    int v = (t < nb) ? partial[t] : 0;
    sm[t] = v;
    __syncthreads();
    for (int off = 1; off < 512; off <<= 1) {
        int u = (t >= off) ? sm[t - off] : 0;
        __syncthreads();
        sm[t] += u;
        __syncthreads();
    }
    if (t < nb) partial[t] = sm[t] - v;  // exclusive
}

__global__ void scan_c_kernel(const int* __restrict__ cnt, const int* __restrict__ partial,
                              int* __restrict__ row_start, int n) {
    __shared__ int sm[256];
    int i = blockIdx.x * 256 + threadIdx.x;
    int v = (i < n) ? cnt[i] : 0;
    sm[threadIdx.x] = v;
    __syncthreads();
    for (int off = 1; off < 256; off <<= 1) {
        int u = (threadIdx.x >= off) ? sm[threadIdx.x - off] : 0;
        __syncthreads();
        sm[threadIdx.x] += u;
        __syncthreads();
    }
    if (i < n) row_start[i + 1] = partial[blockIdx.x] + sm[threadIdx.x];
    if (i == 0) row_start[0] = 0;
}

// int2 CSR entry: .x = src node, .y = float bits of edge weight (ONE 8B scatter/edge)
__global__ void fill_csr_kernel(const int* __restrict__ src, const int* __restrict__ dst,
                                const float* __restrict__ deg, const int* __restrict__ row_start,
                                int* __restrict__ fill, int2* __restrict__ csr2, int e) {
    int i = blockIdx.x * blockDim.x + threadIdx.x;
    if (i < e) {
        int s = src[i], d = dst[i];
        int pos = row_start[d] + atomicAdd(&fill[d], 1);
        float w = 1.0f / sqrtf(deg[s] * deg[d]);
        csr2[pos] = make_int2(s, __float_as_int(w));
    }
}

// ---------------- W pre-convert to fp16 (once) ----------------
__global__ void w_to_half_kernel(const float* __restrict__ W, __half* __restrict__ Wh, int total4) {
    int i = blockIdx.x * blockDim.x + threadIdx.x;
    if (i < total4) {
        float4 v = *(const float4*)&W[i * 4];
        half4v h = {(_Float16)v.x, (_Float16)v.y, (_Float16)v.z, (_Float16)v.w};
        *(half4v*)&((_Float16*)Wh)[i * 4] = h;
    }
}

// ---------------- encoder: m97-style async staging via global_load_lds ----------------
// As: f32 64x64 (16KB, src-swizzled); Bs: f16 128x64 (16KB, src-swizzled). 32KB LDS.
__global__ __launch_bounds__(256) void encoder_mfma_kernel(
    const float* __restrict__ x, const __half* __restrict__ Wh,
    const float* __restrict__ bias, const float* __restrict__ gammas,
    __half* __restrict__ h, __half* __restrict__ acc, int n) {
    __shared__ float As[64 * 64];
    __shared__ _Float16 Bs[128 * 64];
    const int tid = threadIdx.x;
    const int lane = tid & 63;
    const int wid = tid >> 6;
    const int wm = wid >> 1, wn = wid & 1;
    const int row0 = blockIdx.x * 64;
    const int lr = lane & 15;
    const int lk = lane >> 4;        // 0..3
    f32x4 cacc[2][4];
#pragma unroll
    for (int a = 0; a < 2; ++a)
#pragma unroll
        for (int b = 0; b < 4; ++b) cacc[a][b] = (f32x4){0.f, 0.f, 0.f, 0.f};

    for (int k0 = 0; k0 < IN_DIM; k0 += 64) {
        // stage A (x tile, f32): 1024 slots x 16B; slot s -> row r=s>>4, phys grp=s&15
        // source col pre-swizzled so LDS phys grp holds logical (grp ^ (r&7))
#pragma unroll
        for (int q = 0; q < 4; ++q) {
            int s = wid * 256 + q * 64 + lane;
            int r = s >> 4, grp = s & 15;
            int srow = (row0 + r < n) ? (row0 + r) : 0;   // clamp: garbage only affects rows>=n (discarded)
            int col = k0 + ((grp ^ (r & 7)) << 2);
            gload_lds16(&x[(size_t)srow * IN_DIM + col], &As[s * 4]);
        }
        // stage B (Wh tile, f16): 1024 slots x 16B; slot s -> row c=s>>3, phys grp=s&7
#pragma unroll
        for (int q = 0; q < 4; ++q) {
            int s = wid * 256 + q * 64 + lane;
            int c = s >> 3, grp = s & 7;
            int col = k0 + ((grp ^ (c & 7)) << 3);
            gload_lds16(&((const _Float16*)Wh)[(size_t)c * IN_DIM + col], &Bs[s * 8]);
        }
        __syncthreads();   // compiler drains vmcnt before s_barrier
#pragma unroll
        for (int kk = 0; kk < 64; kk += 32) {
            half8v af[2], bf[4];
#pragma unroll
            for (int fm = 0; fm < 2; ++fm) {
                int r = wm * 32 + fm * 16 + lr;
                int g0 = (kk >> 2) + (lk << 1);            // logical f32 group (4 floats)
                int p0 = g0 ^ (r & 7), p1 = (g0 + 1) ^ (r & 7);
                float4 a0 = *(const float4*)&As[r * 64 + p0 * 4];
                float4 a1 = *(const float4*)&As[r * 64 + p1 * 4];
                half8v v;
                v[0] = (_Float16)a0.x; v[1] = (_Float16)a0.y; v[2] = (_Float16)a0.z; v[3] = (_Float16)a0.w;
                v[4] = (_Float16)a1.x; v[5] = (_Float16)a1.y; v[6] = (_Float16)a1.z; v[7] = (_Float16)a1.w;
                af[fm] = v;
            }
#pragma unroll
            for (int fn = 0; fn < 4; ++fn) {
                int c = wn * 64 + fn * 16 + lr;
                int gl = (kk >> 3) + lk;                   // logical f16 group (8 halves)
                int pb = gl ^ (c & 7);
                bf[fn] = *(const half8v*)&Bs[c * 64 + pb * 8];
            }
#pragma unroll
            for (int fm = 0; fm < 2; ++fm)
#pragma unroll
                for (int fn = 0; fn < 4; ++fn)
                    cacc[fm][fn] = __builtin_amdgcn_mfma_f32_16x16x32_f16(
                        af[fm], bf[fn], cacc[fm][fn], 0, 0, 0);
        }
        __syncthreads();
    }
    const float g0v = gammas[0];
    const int orow = (lane >> 4) * 4;   // C/D: col=lane&15, row=(lane>>4)*4+reg (m89)
#pragma unroll
    for (int fm = 0; fm < 2; ++fm) {
#pragma unroll
        for (int r = 0; r < 4; ++r) {
            int row = row0 + wm * 32 + fm * 16 + orow + r;
            if (row < n) {
#pragma unroll
                for (int fn = 0; fn < 4; ++fn) {
                    int col = wn * 64 + fn * 16 + lr;
                    float v = cacc[fm][fn][r] + bias[col];
                    h[(size_t)row * H_DIM + col] = __float2half(v);
                    acc[(size_t)row * H_DIM + col] = __float2half(g0v * v);
                }
            }
        }
    }
}

// ---------------- propagation: wave per node; 4 edges/gather, 16 edges in flight ----------------
__global__ __launch_bounds__(256) void prop_kernel(
    const int* __restrict__ row_start, const int2* __restrict__ csr2,
    const float* __restrict__ inv_deg,
    const __half* __restrict__ hin, __half* __restrict__ hout,
    __half* __restrict__ acc, const float* __restrict__ gammas, int k,
    const int* __restrict__ hpp, int n) {
    const int w = threadIdx.x >> 6;
    const int l = threadIdx.x & 63;
    const int g = l >> 4;        // edge slot within batch of 4
    const int sub = l & 15;      // 8-feature chunk index
    const int i = blockIdx.x * 4 + w;
    if (i >= n) return;
    const int beg = row_start[i], end = row_start[i + 1];
    const half8v* __restrict__ hin8 = (const half8v*)hin;
    float msg[8];
#pragma unroll
    for (int j = 0; j < 8; ++j) msg[j] = 0.f;
    int e = beg;
    // 16 edges in flight (4 batches of 4)
    for (; e + 16 <= end; e += 16) {
        int2 p0 = csr2[e + g];
        int2 p1 = csr2[e + 4 + g];
        int2 p2 = csr2[e + 8 + g];
        int2 p3 = csr2[e + 12 + g];
        half8v v0 = hin8[(size_t)p0.x * 16 + sub];
        half8v v1 = hin8[(size_t)p1.x * 16 + sub];
        half8v v2 = hin8[(size_t)p2.x * 16 + sub];
        half8v v3 = hin8[(size_t)p3.x * 16 + sub];
        float w0 = __int_as_float(p0.y), w1 = __int_as_float(p1.y);
        float w2 = __int_as_float(p2.y), w3 = __int_as_float(p3.y);
#pragma unroll
        for (int j = 0; j < 8; ++j) {
            msg[j] = fmaf(w0, (float)v0[j], msg[j]);
            msg[j] = fmaf(w1, (float)v1[j], msg[j]);
            msg[j] = fmaf(w2, (float)v2[j], msg[j]);
            msg[j] = fmaf(w3, (float)v3[j], msg[j]);
        }
    }
    for (; e + 8 <= end; e += 8) {
        int2 p0 = csr2[e + g];
        int2 p1 = csr2[e + 4 + g];
        half8v v0 = hin8[(size_t)p0.x * 16 + sub];
        half8v v1 = hin8[(size_t)p1.x * 16 + sub];
        float w0 = __int_as_float(p0.y), w1 = __int_as_float(p1.y);
#pragma unroll
        for (int j = 0; j < 8; ++j) {
            msg[j] = fmaf(w0, (float)v0[j], msg[j]);
            msg[j] = fmaf(w1, (float)v1[j], msg[j]);
        }
    }
    // tail: batch of 4 with clamp + zeroed weight
    for (; e < end; e += 4) {
        int idx = e + g;
        int cidx = idx < end ? idx : end - 1;
        int2 p = csr2[cidx];
        float wgt = idx < end ? __int_as_float(p.y) : 0.f;
        half8v v = hin8[(size_t)p.x * 16 + sub];
#pragma unroll
        for (int j = 0; j < 8; ++j) msg[j] = fmaf(wgt, (float)v[j], msg[j]);
    }
    // reduce the 4 edge-groups
#pragma unroll
    for (int j = 0; j < 8; ++j) {
        float m = msg[j];
        m += __shfl_xor(m, 16);
        m += __shfl_xor(m, 32);
        msg[j] = m;
    }
    const float idg = inv_deg[i];
    const half8v s8 = hin8[(size_t)i * 16 + sub];
    const int hp = *hpp;
    float hnew[8];
#pragma unroll
    for (int j = 0; j < 8; ++j) {
        float sf = (float)s8[j];
        float a = fmaf(sf, idg, msg[j]);
        hnew[j] = hp ? (sf - a) : a;
    }
    half8v* hout8 = (half8v*)hout;
    half8v* acc8 = (half8v*)acc;
    if (g == 0) {
        half8v h8;
#pragma unroll
        for (int j = 0; j < 8; ++j) h8[j] = (_Float16)hnew[j];
        hout8[(size_t)i * 16 + sub] = h8;
    } else if (g == 1) {
        const float gm = gammas[k];
        half8v av = acc8[(size_t)i * 16 + sub];
        half8v r;
#pragma unroll
        for (int j = 0; j < 8; ++j) r[j] = (_Float16)fmaf(gm, hnew[j], (float)av[j]);
        acc8[(size_t)i * 16 + sub] = r;
    }
}

// ---------------- BatchNorm statistics ----------------

__global__ __launch_bounds__(128) void bn_partial_kernel(const __half* __restrict__ acc,
                                                         float* __restrict__ sums, int n, int rpb) {
    int f = threadIdx.x;
    int r0 = blockIdx.x * rpb;
    int r1 = min(r0 + rpb, n);
    float s = 0.f, sq = 0.f;
    for (int r = r0; r < r1; ++r) {
        float v = __half2float(acc[(size_t)r * H_DIM + f]);
        s += v;
        sq = fmaf(v, v, sq);
    }
    atomicAdd(&sums[f], s);
    atomicAdd(&sums[H_DIM + f], sq);
}

// fold BN into output GEMM
__global__ __launch_bounds__(128) void bn_prep_kernel(
    const float* __restrict__ sums, const float* __restrict__ bn_gamma,
    const float* __restrict__ bn_beta, const float* __restrict__ W_up,
    const float* __restrict__ b_up, __half* __restrict__ W2h, float* __restrict__ cvec, int n) {
    __shared__ float ss[128], sh[128];
    int t = threadIdx.x;
    float nf = (float)n;
    float mu = sums[t] / nf;
    float var = sums[H_DIM + t] / nf - mu * mu;
    float sc = bn_gamma[t] / sqrtf(var + 1e-5f);
    float shv = bn_beta[t] - mu * sc;
    ss[t] = sc;
    sh[t] = shv;
    __syncthreads();
    float c = b_up[t];
    for (int hh = 0; hh < H_DIM; ++hh) {
        float wv = W_up[(size_t)t * H_DIM + hh];
        W2h[(size_t)t * H_DIM + hh] = __float2half(wv * ss[hh]);
        c = fmaf(wv, sh[hh], c);
    }
    cvec[t] = c;
}

// ---------------- final GEMM + PReLU, MFMA f16, K=128 single tile ----------------
__global__ __launch_bounds__(256) void final_mfma_kernel(
    const __half* __restrict__ accp, const __half* __restrict__ W2,
    const float* __restrict__ cvec, const float* __restrict__ alpha_p,
    float* __restrict__ out, int n) {
    __shared__ _Float16 As[64][128];
    __shared__ _Float16 Bs[128][128];
    const int tid = threadIdx.x;
    const int lane = tid & 63;
    const int wid = tid >> 6;
    const int wm = wid >> 1, wn = wid & 1;
    const int row0 = blockIdx.x * 64;
    const int lr = lane & 15;
    const int lk = (lane >> 4) * 8;
    f32x4 cacc[2][4];
#pragma unroll
    for (int a = 0; a < 2; ++a)
#pragma unroll
        for (int b = 0; b < 4; ++b) cacc[a][b] = (f32x4){0.f, 0.f, 0.f, 0.f};

#pragma unroll
    for (int q = 0; q < 4; ++q) {       // A: 64x128 halves = 1024 x half8v
        int slot = tid * 4 + q;
        int r = slot >> 4;
        int kq = (slot & 15) * 8;
        half8v av = {(_Float16)0, (_Float16)0, (_Float16)0, (_Float16)0,
                     (_Float16)0, (_Float16)0, (_Float16)0, (_Float16)0};
        if (row0 + r < n) av = *(const half8v*)&accp[(size_t)(row0 + r) * H_DIM + kq];
        int idx = kq ^ ((r & 7) << 3);
        *(half8v*)&As[r][idx] = av;
    }
#pragma unroll
    for (int q = 0; q < 8; ++q) {       // B: 128x128 halves = 2048 x half8v
        int slot = tid * 8 + q;
        int c = slot >> 4;
        int kq = (slot & 15) * 8;
        half8v wv = *(const half8v*)&W2[(size_t)c * H_DIM + kq];
        int idx = kq ^ ((c & 7) << 3);
        *(half8v*)&Bs[c][idx] = wv;
    }
    __syncthreads();
#pragma unroll
    for (int kk = 0; kk < 128; kk += 32) {
        half8v af[2], bf[4];
#pragma unroll
        for (int fm = 0; fm < 2; ++fm) {
            int r = wm * 32 + fm * 16 + lr;
            int kx = (kk + lk) ^ ((r & 7) << 3);
            af[fm] = *(const half8v*)&As[r][kx];
        }
#pragma unroll
        for (int fn = 0; fn < 4; ++fn) {
            int c = wn * 64 + fn * 16 + lr;
            int kx = (kk + lk) ^ ((c & 7) << 3);
            bf[fn] = *(const half8v*)&Bs[c][kx];
        }
#pragma unroll
        for (int fm = 0; fm < 2; ++fm)
#pragma unroll
            for (int fn = 0; fn < 4; ++fn)
                cacc[fm][fn] = __builtin_amdgcn_mfma_f32_16x16x32_f16(
                    af[fm], bf[fn], cacc[fm][fn], 0, 0, 0);
    }
    const float al = *alpha_p;
    const int orow = (lane >> 4) * 4;
#pragma unroll
    for (int fm = 0; fm < 2; ++fm) {
#pragma unroll
        for (int r = 0; r < 4; ++r) {
            int row = row0 + wm * 32 + fm * 16 + orow + r;
            if (row < n) {
#pragma unroll
                for (int fn = 0; fn < 4; ++fn) {
                    int col = wn * 64 + fn * 16 + lr;
                    float v = cacc[fm][fn][r] + cvec[col];
                    out[(size_t)row * H_DIM + col] = v > 0.f ? v : al * v;
                }
            }
        }
    }
}

// ---------------- launch ----------------

extern "C" void kernel_launch(void* const* d_in, const int* in_sizes, int n_in,
                              void* d_out, int out_size, void* d_ws, size_t ws_size,
                              hipStream_t stream) {
    const float* x          = (const float*)d_in[0];
    const float* W_enc      = (const float*)d_in[1];
    const float* b_enc      = (const float*)d_in[2];
    const float* gammas     = (const float*)d_in[3];
    const float* bn_gamma   = (const float*)d_in[4];
    const float* bn_beta    = (const float*)d_in[5];
    const float* W_up       = (const float*)d_in[6];
    const float* b_up       = (const float*)d_in[7];
    const float* prelu_al   = (const float*)d_in[8];
    const int*   edge_index = (const int*)d_in[9];
    const int*   high_pass  = (const int*)d_in[10];

    const int H   = in_sizes[2];            // 128
    const int INF = in_sizes[1] / H;        // 512
    const int n   = in_sizes[0] / INF;      // 100000
    const int e   = in_sizes[9] / 2;        // 1600000
    const int K   = in_sizes[3] - 1;        // 10

    const int* src = edge_index;
    const int* dst = edge_index + e;

    char* p = (char*)d_ws;
    auto alloc = [&](size_t bytes) -> char* { char* r = p; p += align256(bytes); return r; };
    int*    cnt       = (int*)alloc((size_t)n * 4);
    int*    fill      = (int*)alloc((size_t)n * 4);
    int*    row_start = (int*)alloc(((size_t)n + 1) * 4);
    int*    partial   = (int*)alloc(4096);
    float*  deg       = (float*)alloc((size_t)n * 4);
    float*  inv_deg   = (float*)alloc((size_t)n * 4);
    int2*   csr2      = (int2*)alloc(((size_t)e + 8) * 8);
    __half* Wh        = (__half*)alloc((size_t)H * INF * 2);
    __half* hkA       = (__half*)alloc((size_t)n * H * 2);
    __half* hkB       = (__half*)alloc((size_t)n * H * 2);
    __half* acc       = (__half*)alloc((size_t)n * H * 2);
    float*  sums      = (float*)alloc(256 * 4);
    __half* W2h       = (__half*)alloc((size_t)H * H * 2);
    float*  cvec      = (float*)alloc((size_t)H * 4);

    hipMemsetAsync(cnt, 0, (size_t)n * 4, stream);
    hipMemsetAsync(fill, 0, (size_t)n * 4, stream);
    hipMemsetAsync(sums, 0, 256 * 4, stream);

    const int gb_e = (e + 255) / 256;
    const int gb_n = (n + 255) / 256;

    count_deg_kernel<<<gb_e, 256, 0, stream>>>(dst, cnt, e);
    deg_fin_kernel<<<gb_n, 256, 0, stream>>>(cnt, deg, inv_deg, n);
    scan_a_kernel<<<gb_n, 256, 0, stream>>>(cnt, partial, n);
    scan_b_kernel<<<1, 512, 0, stream>>>(partial, gb_n);
    scan_c_kernel<<<gb_n, 256, 0, stream>>>(cnt, partial, row_start, n);
    fill_csr_kernel<<<gb_e, 256, 0, stream>>>(src, dst, deg, row_start, fill, csr2, e);

    const int wtotal4 = H * INF / 4;
    w_to_half_kernel<<<(wtotal4 + 255) / 256, 256, 0, stream>>>(W_enc, Wh, wtotal4);

    const int gb_m = (n + 63) / 64;
    encoder_mfma_kernel<<<gb_m, 256, 0, stream>>>(x, Wh, b_enc, gammas, hkA, acc, n);

    __half* cur = hkA;
    __half* nxt = hkB;
    for (int k = 1; k <= K; ++k) {
        prop_kernel<<<(n + 3) / 4, 256, 0, stream>>>(row_start, csr2, inv_deg,
                                                     cur, nxt, acc, gammas, k, high_pass, n);
        __half* t = cur; cur = nxt; nxt = t;
    }

    const int nb_bn = 512;
    const int rpb = (n + nb_bn - 1) / nb_bn;
    bn_partial_kernel<<<nb_bn, 128, 0, stream>>>(acc, sums, n, rpb);
    bn_prep_kernel<<<1, 128, 0, stream>>>(sums, bn_gamma, bn_beta, W_up, b_up, W2h, cvec, n);
    final_mfma_kernel<<<gb_m, 256, 0, stream>>>(acc, W2h, cvec, prelu_al, (float*)d_out, n);
}